// Round 13
// baseline (4755.800 us; speedup 1.0000x reference)
//
#include <hip/hip_runtime.h>

typedef unsigned short u16;
typedef unsigned int u32;
typedef unsigned long long u64;
typedef short v8s __attribute__((ext_vector_type(8)));
typedef float v4f __attribute__((ext_vector_type(4)));
typedef u32 v4u __attribute__((ext_vector_type(4)));

// Dims: B=256, T=512, D=32, H=256, 4H=1024, A=128, HOR=24, NQ=3
// 256 blocks = 16 groups x 16 slices. ONE rendezvous/step (combined u64:
// h0[t]|tag || h1[t-1]|tag). Wave-specialized (R11): waves 0-3 rec, 4-7 attn.
// This revision kills the pre-publish barrier + LDS gate round-trip:
//  - B-frag columns permuted so ALL 4 GATES of a unit live in ONE wave
//    (n = (ln>>2)*256 + gs*16 + wv*4 + (ln&3)); gate gather = 4 __shfl per
//    acc reg; cells run right after the MFMAs; publish BEFORE b2.
//  - spin loads transposed: 16 contiguous u64/thread (one writer/thread);
//    unpack packs in regs and writes 4x ds_write_b128 (was 32x b16).
// b2 retained post-publish (orders attn eP and h0s/h1s reuse). Protocol,
// tags, attn pipe, decoder: identical to R11. (Resubmission of R12 —
// round-12 bench was an infra failure, same as round-8's; design re-audited.)

__device__ __forceinline__ float bf2f(u16 u) { union { u32 u; float f; } c; c.u = ((u32)u) << 16; return c.f; }
__device__ __forceinline__ u16 f2bf(float f) {
  union { float f; u32 u; } c; c.f = f;
  u32 r = c.u + 0x7FFFu + ((c.u >> 16) & 1u);   // RTNE
  return (u16)(r >> 16);
}
__device__ __forceinline__ float sigf(float x) { return 1.f / (1.f + __expf(-x)); }
__device__ __forceinline__ float tanhfast(float x) {
  x = fminf(15.f, fmaxf(-15.f, x));
  float e = __expf(2.f * x);
  return (e - 1.f) / (e + 1.f);
}
__device__ __forceinline__ float ldIn(const void* p, size_t i, int isbf) {
  return isbf ? bf2f(((const u16*)p)[i]) : ((const float*)p)[i];
}
__device__ __forceinline__ v8s ld8hi(const void* p, size_t e, int isbf) {
  if (isbf) return *(const v8s*)((const u16*)p + e);
  const float* f = (const float*)p + e;
  v8s r;
#pragma unroll
  for (int j = 0; j < 8; ++j) r[j] = (short)f2bf(f[j]);
  return r;
}
#define MFMA(a, b, c) __builtin_amdgcn_mfma_f32_16x16x32_bf16(a, b, c, 0, 0, 0)

__device__ __forceinline__ u64 aload64(const u64* p) {
  return __hip_atomic_load(p, __ATOMIC_RELAXED, __HIP_MEMORY_SCOPE_AGENT);
}
__device__ __forceinline__ void astore64(u64* p, u64 v) {
  __hip_atomic_store(p, v, __ATOMIC_RELAXED, __HIP_MEMORY_SCOPE_AGENT);
}

// ---- Decoder tagged stage (unchanged, proven): u64/unit = hi|lo<<16|tag<<32.
__device__ __forceinline__ void stage_dec(u16* dhi, u16* dlo, const u64* src,
                                          int tid, u32 tag) {
  u64 v[16];
#pragma unroll
  for (int i = 0; i < 16; ++i) v[i] = aload64(src + i * 256 + tid);
  bool all;
  do {
    all = true;
#pragma unroll
    for (int i = 0; i < 16; ++i) {
      if ((u32)(v[i] >> 32) != tag) { all = false; v[i] = aload64(src + i * 256 + tid); }
    }
  } while (!all);
#pragma unroll
  for (int i = 0; i < 16; ++i) {
    int idx = i * 256 + tid;
    int row = idx >> 8, col = idx & 255;
    dhi[row * 264 + col] = (u16)v[i];
    dlo[row * 264 + col] = (u16)(v[i] >> 16);
  }
}
__device__ __forceinline__ void stage_f32(u16* dhi, u16* dlo, const float* src, int tid) {
#pragma unroll
  for (int i = 0; i < 8; ++i) {
    int e = i * 512 + tid * 2;
    int row = e >> 8, jc = e & 255;
    float f0 = src[row * 256 + jc], f1 = src[row * 256 + jc + 1];
    u16 h0 = f2bf(f0), h1 = f2bf(f1);
    u16 l0 = f2bf(f0 - bf2f(h0)), l1 = f2bf(f1 - bf2f(h1));
    ((u32*)(dhi + row * 264))[jc >> 1] = (u32)h0 | ((u32)h1 << 16);
    ((u32*)(dlo + row * 264))[jc >> 1] = (u32)l0 | ((u32)l1 << 16);
  }
}

__global__ void sniff_kernel(const u16* __restrict__ w, int* __restrict__ flag) {
  __shared__ int cnt;
  if (threadIdx.x == 0) cnt = 0;
  __syncthreads();
  int ok = 0;
  for (int i = threadIdx.x; i < 1024; i += 256) {
    u16 u = w[2 * i];
    int e = (u >> 7) & 0xFF;
    ok += (u == 0 || (e >= 97 && e <= 140)) ? 1 : 0;
  }
  atomicAdd(&cnt, ok);
  __syncthreads();
  if (threadIdx.x == 0) *flag = (cnt >= 768) ? 1 : 0;
}

// ---------------- Encoder: wave-specialized, gate-local cells, no pre-publish b2 -
__global__ __launch_bounds__(512, 1) void enc_kernel(
    const void* __restrict__ x,
    const void* __restrict__ eWih0, const void* __restrict__ eWhh0, const void* __restrict__ eb0,
    const void* __restrict__ eWih1, const void* __restrict__ eWhh1, const void* __restrict__ eb1,
    const void* __restrict__ aW, const void* __restrict__ aV,
    u64* __restrict__ C,                 // [2 par][grp16][gs16][row16][unit16] u64
    float* __restrict__ ctx, const int* __restrict__ flagp) {
  __shared__ __align__(16) u16 h0s[16 * 264], h1s[16 * 264];
  __shared__ float eP[16 * 132];
  __shared__ __align__(16) u16 xsh[2][16 * 40], xsl[2][16 * 40];  // padded stride 40

  const int isbf = *flagp;
  const int tid = threadIdx.x, blk = blockIdx.x;
  const int grp = blk & 15, gs = blk >> 4;
  const int wv8 = tid >> 6;                      // 0..7
  const int lane = tid & 63;
  const int ln = lane & 15, lq = lane >> 4;

  if (wv8 < 4) {
    // ==================== REC PIPE (waves 0-3, tid 0..255) ====================
    const int wv = wv8;
    const int du = ln & 3;                       // unit within wave's 4
    // B-frag col n(ln) = gate(ln>>2)*256 + gs*16 + wv*4 + du  (gate-local!)
    v8s W0F[9], W1F[16];
    {
      const int gw = (ln >> 2) * 256 + gs * 16 + wv * 4 + du;
      const int kq = lq * 8;
      W0F[0] = ld8hi(eWih0, (size_t)gw * 32 + kq, isbf);
#pragma unroll
      for (int kt = 0; kt < 8; ++kt) {
        W0F[kt + 1] = ld8hi(eWhh0, (size_t)gw * 256 + kt * 32 + kq, isbf);
        W1F[kt]     = ld8hi(eWhh1, (size_t)gw * 256 + kt * 32 + kq, isbf);
        W1F[kt + 8] = ld8hi(eWih1, (size_t)gw * 256 + kt * 32 + kq, isbf);
      }
    }
    float bg0[4], bg1[4];
#pragma unroll
    for (int g = 0; g < 4; ++g) {
      bg0[g] = ldIn(eb0, g * 256 + gs * 16 + wv * 4 + du, isbf);
      bg1[g] = ldIn(eb1, g * 256 + gs * 16 + wv * 4 + du, isbf);
    }
    const int srow = tid & 15, sgs = tid >> 4;   // spin identity (transposed)
    float c0[4] = {0, 0, 0, 0}, c1[4] = {0, 0, 0, 0};
    v8s a0r[8], a1r[8];

    __syncthreads();                             // pb: xs[0] ready

#pragma unroll 1
    for (int t = 0; t < 514; ++t) {
      const int rPar = (t + 1) & 1, wPar = t & 1;
      const u32 tag = (u32)(u16)t;
      // ---- S1: transposed spin (16 contiguous u64 = one writer's row slice)
      {
        const u64* src = C + (size_t)rPar * 65536 + grp * 4096 + tid * 16;
        u64 v[16];
#pragma unroll
        for (int i = 0; i < 16; ++i) v[i] = aload64(src + i);
        bool all;
        do {
          all = true;
#pragma unroll
          for (int i = 0; i < 16; ++i) {
            u64 w = v[i];
            if (!((((w >> 16) & 0xFFFFull) == tag) && ((w >> 48) == tag))) {
              all = false;
              v[i] = aload64(src + i);
            }
          }
        } while (!all);
        u32 q0[8], q1[8];
#pragma unroll
        for (int i = 0; i < 8; ++i) {
          u64 w0 = v[2 * i], w1 = v[2 * i + 1];
          q0[i] = (u32)(w0 & 0xFFFF) | (((u32)(w1 & 0xFFFF)) << 16);
          q1[i] = (u32)((w0 >> 32) & 0xFFFF) | (((u32)((w1 >> 32) & 0xFFFF)) << 16);
        }
        *(v4u*)(h0s + srow * 264 + sgs * 16)     = v4u{q0[0], q0[1], q0[2], q0[3]};
        *(v4u*)(h0s + srow * 264 + sgs * 16 + 8) = v4u{q0[4], q0[5], q0[6], q0[7]};
        *(v4u*)(h1s + srow * 264 + sgs * 16)     = v4u{q1[0], q1[1], q1[2], q1[3]};
        *(v4u*)(h1s + srow * 264 + sgs * 16 + 8) = v4u{q1[4], q1[5], q1[6], q1[7]};
      }
      __syncthreads();                           // b1: h0s/h1s ready

      // ---- P1: frag reads + 25 MFMAs (split chains)
#pragma unroll
      for (int kt = 0; kt < 8; ++kt) {
        const int off = ln * 264 + kt * 32 + lq * 8;
        a0r[kt] = *(const v8s*)(h0s + off);
        a1r[kt] = *(const v8s*)(h1s + off);
      }
      v4f acc0 = {0, 0, 0, 0}, acc1 = {0, 0, 0, 0};
      if (t < 512) {
        v8s xh = *(const v8s*)(xsh[t & 1] + ln * 40 + lq * 8);
        v4f A = {0, 0, 0, 0}, B = {0, 0, 0, 0};
        A = MFMA(xh, W0F[0], A);
        if (!isbf) {
          v8s xl = *(const v8s*)(xsl[t & 1] + ln * 40 + lq * 8);
          A = MFMA(xl, W0F[0], A);
        }
#pragma unroll
        for (int kt = 0; kt < 4; ++kt) A = MFMA(a0r[kt], W0F[kt + 1], A);
#pragma unroll
        for (int kt = 4; kt < 8; ++kt) B = MFMA(a0r[kt], W0F[kt + 1], B);
#pragma unroll
        for (int r = 0; r < 4; ++r) acc0[r] = A[r] + B[r];
      }
      if (t <= 512) {
        v4f A = {0, 0, 0, 0}, B = {0, 0, 0, 0};
#pragma unroll
        for (int kt = 0; kt < 8; ++kt) {
          A = MFMA(a0r[kt], W1F[kt + 8], A);
          B = MFMA(a1r[kt], W1F[kt], B);
        }
#pragma unroll
        for (int r = 0; r < 4; ++r) acc1[r] = A[r] + B[r];
      }

      // ---- P2: gate gather via shuffles, cells in-wave, publish (pre-b2!)
      const u32 tagS = (u32)(u16)(t + 1) << 16;
      if (t <= 512) {
#pragma unroll
        for (int r = 0; r < 4; ++r) {
          u32 w0 = tagS, w1 = tagS;              // defaults: value 0
          if (t < 512) {
            float gi = __shfl(acc0[r], lq * 16 + du)      + bg0[0];
            float gf = __shfl(acc0[r], lq * 16 + 4 + du)  + bg0[1];
            float gg = __shfl(acc0[r], lq * 16 + 8 + du)  + bg0[2];
            float go = __shfl(acc0[r], lq * 16 + 12 + du) + bg0[3];
            c0[r] = sigf(gf) * c0[r] + sigf(gi) * tanhfast(gg);
            float h = sigf(go) * tanhfast(c0[r]);
            w0 |= (u32)f2bf(h);
          }
          if (t >= 1) {
            float gi = __shfl(acc1[r], lq * 16 + du)      + bg1[0];
            float gf = __shfl(acc1[r], lq * 16 + 4 + du)  + bg1[1];
            float gg = __shfl(acc1[r], lq * 16 + 8 + du)  + bg1[2];
            float go = __shfl(acc1[r], lq * 16 + 12 + du) + bg1[3];
            c1[r] = sigf(gf) * c1[r] + sigf(gi) * tanhfast(gg);
            float h = sigf(go) * tanhfast(c1[r]);
            w1 |= (u32)f2bf(h);
          }
          if (ln < 4)
            astore64(C + (size_t)wPar * 65536 + grp * 4096 + gs * 256 +
                         (lq * 4 + r) * 16 + wv * 4 + du,
                     (u64)w0 | ((u64)w1 << 32));
        }
      }
      __syncthreads();                           // b2 (post-publish; orders eP/h reuse)
    }
  } else {
    // ==================== ATTN PIPE (waves 4-7, tid 256..511) ====================
    const int aw = wv8 - 4;
    v8s AWF[16];
    {
      const int kq = lq * 8;
#pragma unroll
      for (int kt = 0; kt < 8; ++kt)
#pragma unroll
        for (int j2 = 0; j2 < 2; ++j2) {
          v8s f;
          int ac = (2 * aw + j2) * 16 + ln;
#pragma unroll
          for (int j = 0; j < 8; ++j)
            f[j] = (short)f2bf(ldIn(aW, (size_t)(kt * 32 + kq + j) * 128 + ac, isbf));
          AWF[kt * 2 + j2] = f;
        }
    }
    const int tid2 = tid - 256;
    const int urow2 = tid2 >> 4, uu2 = tid2 & 15;
    const int gUnit2 = gs * 16 + uu2;
    float aVr[8];
#pragma unroll
    for (int j = 0; j < 8; ++j) aVr[j] = ldIn(aV, (size_t)(uu2 + 16 * j), isbf);

    float mS = -3e38f, lS = 0.f, ctxA = 0.f;

    const int xe = tid2 * 2, xrow = xe >> 5, xcol = xe & 31;
    const size_t xbase = ((size_t)(grp * 16 + xrow) * 512) * 32 + xcol;

    // prologue: prep x[0] -> xs[0]
    {
      if (isbf) {
        u32 v = *(const u32*)((const u16*)x + xbase);
        *(u32*)(xsh[0] + xrow * 40 + xcol) = v;
        *(u32*)(xsl[0] + xrow * 40 + xcol) = 0;
      } else {
        const float* f = (const float*)x + xbase;
        float f0 = f[0], f1 = f[1];
        u16 h0 = f2bf(f0), h1 = f2bf(f1);
        u16 l0 = f2bf(f0 - bf2f(h0)), l1 = f2bf(f1 - bf2f(h1));
        *(u32*)(xsh[0] + xrow * 40 + xcol) = (u32)h0 | ((u32)h1 << 16);
        *(u32*)(xsl[0] + xrow * 40 + xcol) = (u32)l0 | ((u32)l1 << 16);
      }
    }
    __syncthreads();                             // pb: xs[0] ready

#pragma unroll 1
    for (int t = 0; t < 514; ++t) {
      // ---- pre-b1: prep x[t+1] -> xs[(t+1)&1]
      if (t < 511) {
        const int par = (t + 1) & 1;
        const size_t off = xbase + (size_t)(t + 1) * 32;
        if (isbf) {
          u32 v = *(const u32*)((const u16*)x + off);
          *(u32*)(xsh[par] + xrow * 40 + xcol) = v;
        } else {
          const float* f = (const float*)x + off;
          float f0 = f[0], f1 = f[1];
          u16 h0 = f2bf(f0), h1 = f2bf(f1);
          u16 l0 = f2bf(f0 - bf2f(h0)), l1 = f2bf(f1 - bf2f(h1));
          *(u32*)(xsh[par] + xrow * 40 + xcol) = (u32)h0 | ((u32)h1 << 16);
          *(u32*)(xsl[par] + xrow * 40 + xcol) = (u32)l0 | ((u32)l1 << 16);
        }
      }
      __syncthreads();                           // b1: h0s/h1s ready

      // ---- post-b1: attention MFMAs on h1s (= h1[t-2]); eP write; h1v
      float h1v = 0.f;
      if (t >= 2) {
        v4f A = {0, 0, 0, 0}, B = {0, 0, 0, 0};
#pragma unroll
        for (int kt = 0; kt < 8; ++kt) {
          v8s a1 = *(const v8s*)(h1s + ln * 264 + kt * 32 + lq * 8);
          A = MFMA(a1, AWF[kt * 2], A);
          B = MFMA(a1, AWF[kt * 2 + 1], B);
        }
#pragma unroll
        for (int r = 0; r < 4; ++r) {
          eP[(lq * 4 + r) * 132 + (2 * aw) * 16 + ln] = A[r];
          eP[(lq * 4 + r) * 132 + (2 * aw + 1) * 16 + ln] = B[r];
        }
        h1v = bf2f(h1s[urow2 * 264 + gUnit2]);
      }
      __syncthreads();                           // b2

      // ---- post-b2: softmax tail for h1[t-2]
      if (t >= 2) {
        float e = 0.f;
#pragma unroll
        for (int j = 0; j < 8; ++j)
          e += tanhfast(eP[urow2 * 132 + uu2 + 16 * j]) * aVr[j];
        e += __shfl_xor(e, 1);
        e += __shfl_xor(e, 2);
        e += __shfl_xor(e, 4);
        e += __shfl_xor(e, 8);
        float nm = fmaxf(mS, e);
        float al = __expf(mS - nm), p = __expf(e - nm);
        lS = lS * al + p;
        ctxA = ctxA * al + p * h1v;
        mS = nm;
      }
    }
    ctx[(size_t)(grp * 16 + urow2) * 256 + gUnit2] = ctxA / lS;
  }
}

// ---------------- Decoder: 24 steps x 2 sub-steps + projection (unchanged) -------
__global__ __launch_bounds__(256, 1) void dec_kernel(
    const void* __restrict__ x,
    const void* __restrict__ dWih0, const void* __restrict__ dWhh0, const void* __restrict__ db0,
    const void* __restrict__ dWih1, const void* __restrict__ dWhh1, const void* __restrict__ db1,
    const void* __restrict__ qW, const void* __restrict__ qb,
    const float* __restrict__ ctx,
    u64* __restrict__ H0d, u64* __restrict__ H1d, u64* __restrict__ dinpG,
    void* __restrict__ out, const int* __restrict__ flagp) {
  __shared__ u16 sAhi[16 * 264], sAlo[16 * 264], sBhi[16 * 264], sBlo[16 * 264];
  __shared__ float gb[16 * 64];
  __shared__ float dinpS[16];

  const int isbf = *flagp;
  const int tid = threadIdx.x, blk = blockIdx.x;
  const int grp = blk & 15, gs = blk >> 4;
  const int lane = tid & 63, wv = tid >> 6;
  const int ln = lane & 15, lq = lane >> 4;

  v8s W0F[8], W1F[16];
  {
    const int gw = wv * 256 + gs * 16 + ln;
    const int kq = lq * 8;
#pragma unroll
    for (int kt = 0; kt < 8; ++kt) {
      W0F[kt]     = ld8hi(dWhh0, (size_t)gw * 256 + kt * 32 + kq, isbf);
      W1F[kt]     = ld8hi(dWhh1, (size_t)gw * 256 + kt * 32 + kq, isbf);
      W1F[kt + 8] = ld8hi(dWih1, (size_t)gw * 256 + kt * 32 + kq, isbf);
    }
  }
  const int urow = tid >> 4, uu = tid & 15;
  float bg0[4], bg1[4], w0v[4];
#pragma unroll
  for (int g = 0; g < 4; ++g) {
    bg0[g] = ldIn(db0, g * 256 + gs * 16 + uu, isbf);
    bg1[g] = ldIn(db1, g * 256 + gs * 16 + uu, isbf);
    w0v[g] = ldIn(dWih0, g * 256 + gs * 16 + uu, isbf);
  }
  const int gRowU = grp * 16 + urow;
  const int gUnit = gs * 16 + uu;

  float c0 = ctx[(size_t)gRowU * 256 + gUnit];
  float c1 = c0;

#pragma unroll 1
  for (int t = 0; t < 24; ++t) {
    const int pPrev = (t + 1) & 1, pCur = t & 1;
    if (t == 0) {
      stage_f32(sAhi, sAlo, ctx + (size_t)grp * 16 * 256, tid);
      if (tid < 16)
        dinpS[tid] = ldIn(x, ((size_t)(grp * 16 + tid) * 512 + 511) * 32 + 31, isbf);
    } else {
      stage_dec(sAhi, sAlo, H0d + (size_t)pPrev * 65536 + grp * 4096, tid, (u32)(2 * t - 1));
      if (tid < 16) {
        u64 w;
        do { w = aload64(dinpG + pPrev * 256 + grp * 16 + tid); } while ((u32)(w >> 32) != (u32)(2 * t));
        dinpS[tid] = __uint_as_float((u32)w);
      }
    }
    __syncthreads();
    v4f acc = {0, 0, 0, 0};
#pragma unroll
    for (int kt = 0; kt < 8; ++kt) {
      const int off = ln * 264 + kt * 32 + lq * 8;
      acc = MFMA(*(const v8s*)(sAhi + off), W0F[kt], acc);
      acc = MFMA(*(const v8s*)(sAlo + off), W0F[kt], acc);
    }
    {
      const int bR = lq * 4;
#pragma unroll
      for (int r = 0; r < 4; ++r) gb[(bR + r) * 64 + ln * 4 + wv] = acc[r];
    }
    float di = dinpS[urow];
    __syncthreads();
    {
      const float* g0 = gb + (urow * 16 + uu) * 4;
      float gi = g0[0] + bg0[0] + di * w0v[0];
      float gf = g0[1] + bg0[1] + di * w0v[1];
      float gg = g0[2] + bg0[2] + di * w0v[2];
      float go = g0[3] + bg0[3] + di * w0v[3];
      c0 = sigf(gf) * c0 + sigf(gi) * tanhfast(gg);
      float h = sigf(go) * tanhfast(c0);
      u16 hh = f2bf(h); u16 hl = f2bf(h - bf2f(hh));
      astore64(H0d + (size_t)pCur * 65536 + gRowU * 256 + gUnit,
               (u64)hh | ((u64)hl << 16) | ((u64)(u32)(2 * t + 1) << 32));
    }
    if (t == 0) stage_f32(sBhi, sBlo, ctx + (size_t)grp * 16 * 256, tid);
    else stage_dec(sBhi, sBlo, H1d + (size_t)pPrev * 65536 + grp * 4096, tid, (u32)(2 * t));
    stage_dec(sAhi, sAlo, H0d + (size_t)pCur * 65536 + grp * 4096, tid, (u32)(2 * t + 1));
    __syncthreads();
    v4f a1 = {0, 0, 0, 0};
#pragma unroll
    for (int kt = 0; kt < 8; ++kt) {
      const int off = ln * 264 + kt * 32 + lq * 8;
      a1 = MFMA(*(const v8s*)(sBhi + off), W1F[kt], a1);
      a1 = MFMA(*(const v8s*)(sBlo + off), W1F[kt], a1);
      a1 = MFMA(*(const v8s*)(sAhi + off), W1F[kt + 8], a1);
      a1 = MFMA(*(const v8s*)(sAlo + off), W1F[kt + 8], a1);
    }
    {
      const int bR = lq * 4;
#pragma unroll
      for (int r = 0; r < 4; ++r) gb[(bR + r) * 64 + ln * 4 + wv] = a1[r];
    }
    __syncthreads();
    {
      const float* g1 = gb + (urow * 16 + uu) * 4;
      float gi = g1[0] + bg1[0], gf = g1[1] + bg1[1], gg = g1[2] + bg1[2], go = g1[3] + bg1[3];
      c1 = sigf(gf) * c1 + sigf(gi) * tanhfast(gg);
      float h = sigf(go) * tanhfast(c1);
      u16 hh = f2bf(h); u16 hl = f2bf(h - bf2f(hh));
      astore64(H1d + (size_t)pCur * 65536 + gRowU * 256 + gUnit,
               (u64)hh | ((u64)hl << 16) | ((u64)(u32)(2 * t + 2) << 32));
      if (gUnit == 0)
        astore64(dinpG + pCur * 256 + gRowU,
                 (u64)__float_as_uint(h) | ((u64)(u32)(2 * t + 2) << 32));
    }
  }
  stage_dec(sAhi, sAlo, H1d + (size_t)65536 + grp * 4096, tid, 48u);
  __syncthreads();
  if (gs < 12 && tid < 96) {
    int r = tid / 6, p = tid % 6;
    int qo = gs * 6 + p, row = grp * 16 + r;
    float s = ldIn(qb, qo, isbf);
    for (int h = 0; h < 256; ++h)
      s += (bf2f(sAhi[r * 264 + h]) + bf2f(sAlo[r * 264 + h])) * ldIn(qW, (size_t)qo * 256 + h, isbf);
    if (isbf) ((u16*)out)[row * 72 + qo] = f2bf(s);
    else      ((float*)out)[row * 72 + qo] = s;
  }
}

extern "C" void kernel_launch(void* const* d_in, const int* in_sizes, int n_in,
                              void* d_out, int out_size, void* d_ws, size_t ws_size,
                              hipStream_t stream) {
  const void* x     = d_in[0];
  const void* eWih0 = d_in[1];
  const void* eWhh0 = d_in[2];
  const void* eb0   = d_in[3];
  const void* eWih1 = d_in[4];
  const void* eWhh1 = d_in[5];
  const void* eb1   = d_in[6];
  const void* dWih0 = d_in[7];
  const void* dWhh0 = d_in[8];
  const void* db0   = d_in[9];
  const void* dWih1 = d_in[10];
  const void* dWhh1 = d_in[11];
  const void* db1   = d_in[12];
  const void* aW    = d_in[13];
  const void* aV    = d_in[14];
  const void* qW    = d_in[15];
  const void* qb    = d_in[16];

  char* wsb = (char*)d_ws;
  u64*   C     = (u64*)(wsb + 0);              // [2][16][16][16][16] u64 = 1,048,576
  u64*   H0d   = (u64*)(wsb + 1048576);        // [2][256][256] u64 = 1,048,576
  u64*   H1d   = (u64*)(wsb + 2097152);        // -> 3,145,728
  u64*   dinpG = (u64*)(wsb + 3145728);        // [2][256] u64 = 4,096 -> 3,149,824
  int*   flag  = (int*)(wsb + 3149824);        // 256 -> 3,150,080
  float* ctx   = (float*)(wsb + 3150080);      // 262,144 -> 3,412,224
  // total ws: 3,412,224 bytes. All tagged buffers zeroed each launch.

  hipMemsetAsync(wsb, 0, 3149824, stream);

  sniff_kernel<<<1, 256, 0, stream>>>((const u16*)eWhh0, flag);
  enc_kernel<<<256, 512, 0, stream>>>(x, eWih0, eWhh0, eb0, eWih1, eWhh1, eb1,
                                      aW, aV, C, ctx, flag);
  dec_kernel<<<256, 256, 0, stream>>>(x, dWih0, dWhh0, db0, dWih1, dWhh1, db1,
                                      qW, qb, ctx, H0d, H1d, dinpG,
                                      d_out, flag);
}